// Round 1
// baseline (214.564 us; speedup 1.0000x reference)
//
#include <hip/hip_runtime.h>
#include <stdint.h>

typedef unsigned long long u64;
typedef __attribute__((ext_vector_type(4))) float floatx4;
typedef __attribute__((ext_vector_type(2))) long longx2;

#define NPOS   65536
#define CDIM   256
#define KCODES 1024

__device__ __forceinline__ void gload16(const void* g, void* l) {
    __builtin_amdgcn_global_load_lds((const __attribute__((address_space(1))) void*)g,
                                     (__attribute__((address_space(3))) void*)l, 16, 0, 0);
}
__device__ __forceinline__ unsigned pk4_fp8(float a, float b, float c, float d) {
    int u = __builtin_amdgcn_cvt_pk_fp8_f32(a, b, 0, false);
    u = __builtin_amdgcn_cvt_pk_fp8_f32(c, d, u, true);
    return (unsigned)u;
}

// ---------------- emb -> emb8 [kt][k][64B] fp8(256*e), K-permuted; e_sqs = 4096*e_sq
// Layout: byte(kt,k,q,ks,j0) = kt*65536 + k*64 + q*16 + ks*8 + j0
//   (kt = c>>6, ks = (c&63)>>5, q = (c&31)>>3, j0 = c&7)
// A wave's fb read (16 rows x 4 q-chunks) is then a permuted-contiguous 1KB block.
__global__ void emb_prep(const float* __restrict__ emb, unsigned char* __restrict__ emb8,
                         float* __restrict__ e_sqs) {
    int k = blockIdx.x, l = threadIdx.x;            // 64 lanes
    float4 v = ((const float4*)(emb + (size_t)k * CDIM))[l];
    float s = v.x * v.x + v.y * v.y + v.z * v.z + v.w * v.w;
    int c = l * 4;
    int kt = c >> 6, cl = c & 63;
    int ks = cl >> 5, q = (cl & 31) >> 3, j0 = cl & 7;
    unsigned pk = pk4_fp8(v.x * 256.f, v.y * 256.f, v.z * 256.f, v.w * 256.f);
    *(unsigned*)(emb8 + ((size_t)kt << 16) + (size_t)k * 64 + q * 16 + ks * 8 + j0) = pk;
#pragma unroll
    for (int off = 32; off >= 1; off >>= 1) s += __shfl_down(s, off, 64);
    if (l == 0) e_sqs[k] = 4096.f * s;
}

// ---------------- fused: transpose+fp8 convert, fp8 MFMA argmin (B direct from L2),
//                  gather, loss. K-loop is barrier-free.
__global__ __launch_bounds__(256, 5)
void vq_fused(const float* __restrict__ z, const float* __restrict__ emb,
              const unsigned char* __restrict__ emb8, const float* __restrict__ e_sqs,
              float* __restrict__ out, float* __restrict__ loss)
{
    __shared__ __align__(16) char smem[18944];
    unsigned char* As = (unsigned char*)smem;            // [64 p][256B] K-permuted+swizzled
    float*  z2p    = (float*)(smem + 16384);             // [4][64]
    float*  z2     = (float*)(smem + 17408);             // [64]
    unsigned* red  = (unsigned*)(smem + 17664);          // [64][4]
    unsigned* sidx = (unsigned*)(smem + 18688);          // [64]
    float*  smG    = (float*)smem;                       // [16][256] overlay, chunk-swizzled

    const int tid = threadIdx.x, wave = tid >> 6, lane = tid & 63;
    const int q = lane >> 4, r = lane & 15;
    const int m0 = blockIdx.x << 6;
    const int b = m0 >> 10, s0 = m0 & 1023;

    // ---- phase 0: load z, z_sq, convert 16*z -> fp8, K-permute+swizzle into As ----
    {
        const int p = tid & 63, cg = tid >> 6;
        const float* zb = z + ((size_t)(b * 256 + cg * 64)) * 1024 + s0 + p;
        float ps = 0.f;
#pragma unroll
        for (int qq = 0; qq < 4; ++qq)
#pragma unroll
            for (int ks = 0; ks < 2; ++ks) {
                float v[8];
#pragma unroll
                for (int j = 0; j < 8; ++j) {
                    v[j] = zb[(size_t)(ks * 32 + qq * 8 + j) * 1024];
                    ps = fmaf(v[j], v[j], ps);
                }
                uint2 w;
                w.x = pk4_fp8(16.f * v[0], 16.f * v[1], 16.f * v[2], 16.f * v[3]);
                w.y = pk4_fp8(16.f * v[4], 16.f * v[5], 16.f * v[6], 16.f * v[7]);
                const int pgl = cg * 4 + qq;
                const int pgs = (pgl & 8) | ((pgl & 7) ^ (p & 7));
                *(uint2*)(As + p * 256 + pgs * 16 + ks * 8) = w;
            }
        z2p[cg * 64 + p] = ps;
    }
    __syncthreads();
    if (tid < 64)
        z2[tid] = (z2p[tid] + z2p[64 + tid]) + (z2p[128 + tid] + z2p[192 + tid]);

    // ---- K-loop: 8 n-chunks of 128 codes, B fragments straight from L2, no barriers ----
    floatx4 acc[4][2] = {};
    unsigned run[16];
#pragma unroll
    for (int j = 0; j < 16; ++j) run[j] = 0xFFFFFFFFu;

    const unsigned char* ebase = emb8 + (size_t)(wave * 32 + r) * 64 + q * 16;

#pragma unroll 1
    for (int nc = 0; nc < 8; ++nc) {
        const int n0 = nc << 7;
#pragma unroll
        for (int kt = 0; kt < 4; ++kt) {
            longx2 fa[4], fb[2];
#pragma unroll
            for (int mt = 0; mt < 4; ++mt) {
                const int p = mt * 16 + r;
                const int pgl = kt * 4 + q;
                const int pgs = (pgl & 8) | ((pgl & 7) ^ (r & 7));
                fa[mt] = *(const longx2*)(As + p * 256 + pgs * 16);
            }
#pragma unroll
            for (int nt = 0; nt < 2; ++nt)
                fb[nt] = *(const longx2*)(ebase + ((size_t)kt << 16) +
                                          (size_t)(n0 + nt * 16) * 64);
#pragma unroll
            for (int mt = 0; mt < 4; ++mt)
#pragma unroll
                for (int nt = 0; nt < 2; ++nt) {
                    acc[mt][nt] = __builtin_amdgcn_mfma_f32_16x16x32_fp8_fp8(
                        fa[mt][0], fb[nt][0], acc[mt][nt], 0, 0, 0);
                    acc[mt][nt] = __builtin_amdgcn_mfma_f32_16x16x32_fp8_fp8(
                        fa[mt][1], fb[nt][1], acc[mt][nt], 0, 0, 0);
                }
        }
        // fold: val = 16384 + 4096*e_sq - 2*dot~  (positive); pack u32: (val*32)<<10 | k
        float ev[2];
#pragma unroll
        for (int nt = 0; nt < 2; ++nt) ev[nt] = e_sqs[n0 + wave * 32 + nt * 16 + r];
#pragma unroll
        for (int mt = 0; mt < 4; ++mt) {
#pragma unroll
            for (int reg = 0; reg < 4; ++reg) {
                float mv = 3e7f; int mk = 0;
#pragma unroll
                for (int nt = 0; nt < 2; ++nt) {
                    float v = 16384.f + ev[nt] - 2.f * acc[mt][nt][reg];
                    if (v < mv) { mv = v; mk = n0 + wave * 32 + nt * 16 + r; }
                }
                unsigned pk = ((unsigned)(mv * 32.f) << 10) | (unsigned)mk;
                run[(mt << 2) + reg] = min(run[(mt << 2) + reg], pk);
            }
#pragma unroll
            for (int nt = 0; nt < 2; ++nt) acc[mt][nt] = (floatx4){0.f, 0.f, 0.f, 0.f};
        }
    }

    // ---- argmin merge across lanes/waves ----
#pragma unroll
    for (int j = 0; j < 16; ++j) {
        unsigned pk = run[j];
#pragma unroll
        for (int off = 1; off < 16; off <<= 1)
            pk = min(pk, (unsigned)__shfl_xor((int)pk, off, 64));
        if (r == 0)
            red[(((j >> 2) << 4) + (q << 2) + (j & 3)) * 4 + wave] = pk;
    }
    __syncthreads();
    if (tid < 64) {
        unsigned m = min(min(red[tid * 4 + 0], red[tid * 4 + 1]),
                         min(red[tid * 4 + 2], red[tid * 4 + 3]));
        sidx[tid] = m & 1023u;
        float val = (float)(m >> 10) * (1.f / 32.f);
        float d = z2[tid] + (val - 16384.f) * (1.f / 4096.f);
#pragma unroll
        for (int off = 32; off >= 1; off >>= 1) d += __shfl_down(d, off, 64);
        if (tid == 0) atomicAdd(loss, d * (1.25f / 16777216.f));
    }
    __syncthreads();

    // ---- gather + write z_q: 4 passes of 16 rows through smG overlay ----
    // smG row rr: linear gload16 dest; global source chunk pre-swizzled
    // (chunk ^ (rr&7)) so the column-slice reads below are bank-spread (G4/T2).
    for (int pass = 0; pass < 4; ++pass) {
        const int rbase = pass << 4;
#pragma unroll
        for (int i = 0; i < 4; ++i) {
            const int rr = wave * 4 + i;                              // smG row 0..15
            const unsigned code = sidx[rbase + rr];
            const int src_chunk = (lane & 56) | ((lane & 7) ^ (rr & 7));
            gload16(emb + (size_t)code * CDIM + src_chunk * 4,
                    smG + rr * 256);
        }
        __syncthreads();
        {
            const int s = tid & 15, cg = tid >> 4;                    // 16 pos x 16ch-groups
            float* ob = out + ((size_t)(b * 256 + cg * 16)) * 1024 + s0 + rbase + s;
#pragma unroll
            for (int j4 = 0; j4 < 4; ++j4) {
                const int c = cg * 4 + j4;                            // logical 16B chunk
                const int p = (c & 56) | ((c & 7) ^ (s & 7));         // swizzled position
                float4 v = *(const float4*)(smG + s * 256 + p * 4);
                ob[(size_t)(j4 * 4 + 0) * 1024] = v.x;
                ob[(size_t)(j4 * 4 + 1) * 1024] = v.y;
                ob[(size_t)(j4 * 4 + 2) * 1024] = v.z;
                ob[(size_t)(j4 * 4 + 3) * 1024] = v.w;
            }
        }
        __syncthreads();
    }
}

extern "C" void kernel_launch(void* const* d_in, const int* in_sizes, int n_in,
                              void* d_out, int out_size, void* d_ws, size_t ws_size,
                              hipStream_t stream)
{
    const float* z   = (const float*)d_in[0];
    const float* emb = (const float*)d_in[1];
    float* out = (float*)d_out;

    unsigned char* emb8 = (unsigned char*)d_ws;           // 256 KB
    float* e_sqs = (float*)((char*)d_ws + 262144);        // 4 KB
    float* loss  = out + 16777216;

    hipMemsetAsync(loss, 0, sizeof(float), stream);
    emb_prep<<<KCODES, 64, 0, stream>>>(emb, emb8, e_sqs);
    vq_fused<<<1024, 256, 0, stream>>>(z, emb, emb8, e_sqs, out, loss);
}

// Round 2
// 148.613 us; speedup vs baseline: 1.4438x; 1.4438x over previous
//
#include <hip/hip_runtime.h>
#include <stdint.h>

typedef __attribute__((ext_vector_type(4))) float floatx4;
typedef __attribute__((ext_vector_type(2))) long longx2;

#define CDIM   256
#define KCODES 1024

__device__ __forceinline__ void gload16(const void* g, void* l) {
    __builtin_amdgcn_global_load_lds((const __attribute__((address_space(1))) void*)g,
                                     (__attribute__((address_space(3))) void*)l, 16, 0, 0);
}
__device__ __forceinline__ unsigned pk4_fp8(float a, float b, float c, float d) {
    int u = __builtin_amdgcn_cvt_pk_fp8_f32(a, b, 0, false);
    u = __builtin_amdgcn_cvt_pk_fp8_f32(c, d, u, true);
    return (unsigned)u;
}

// ---------------- emb -> emb8 [kt][k][64B] fp8(256*e), K-permuted; e_sqs = 4096*e_sq
// byte(kt,k,q,ks,j0) = kt*65536 + k*64 + q*16 + ks*8 + j0
//   (kt = c>>6, ks = (c&63)>>5, q = (c&31)>>3, j0 = c&7)
__global__ void emb_prep(const float* __restrict__ emb, unsigned char* __restrict__ emb8,
                         float* __restrict__ e_sqs) {
    int k = blockIdx.x, l = threadIdx.x;            // 64 lanes
    float4 v = ((const float4*)(emb + (size_t)k * CDIM))[l];
    float s = v.x * v.x + v.y * v.y + v.z * v.z + v.w * v.w;
    int c = l * 4;
    int kt = c >> 6, cl = c & 63;
    int ks = cl >> 5, q = (cl & 31) >> 3, j0 = cl & 7;
    unsigned pk = pk4_fp8(v.x * 256.f, v.y * 256.f, v.z * 256.f, v.w * 256.f);
    *(unsigned*)(emb8 + ((size_t)kt << 16) + (size_t)k * 64 + q * 16 + ks * 8 + j0) = pk;
#pragma unroll
    for (int off = 32; off >= 1; off >>= 1) s += __shfl_down(s, off, 64);
    if (l == 0) e_sqs[k] = 4096.f * s;
}

// ---------------- fused: transpose+fp8 convert, fp8 MFMA argmin (B LDS-staged,
//                  prefetch-pipelined, A-fragments hoisted to regs), gather, loss
__global__ __launch_bounds__(256, 4)
void vq_fused(const float* __restrict__ z, const float* __restrict__ emb,
              const unsigned char* __restrict__ emb8, const float* __restrict__ e_sqs,
              float* __restrict__ out, float* __restrict__ loss)
{
    __shared__ __align__(16) char smem[34304];
    // overlays:
    //   phase 0 : As  = smem[0..16384)  [64 pos][256B], z2p = smem[16384..17408)
    //   K-loop  : Bs dbuf = smem[0..16384) / smem[16384..32768)  [kt4][lc64][64B]
    //   output  : smG = smem[0..32768)  [32 rows][1KB], chunk-swizzled
    unsigned char* As = (unsigned char*)smem;
    float*  z2p    = (float*)(smem + 16384);             // [4][64]
    float*  z2     = (float*)(smem + 32768);             // [64]
    unsigned* red  = (unsigned*)(smem + 33024);          // [64][4]
    unsigned* sidx = (unsigned*)(smem + 34048);          // [64]

    const int tid = threadIdx.x, wave = tid >> 6, lane = tid & 63;
    const int q = lane >> 4, r = lane & 15;
    const int m0 = blockIdx.x << 6;
    const int b = m0 >> 10, s0 = m0 & 1023;

    // ---- phase 0: load z, z_sq, convert 16*z -> fp8, K-permute+swizzle into As ----
    {
        const int p = tid & 63, cg = tid >> 6;
        const float* zb = z + ((size_t)(b * 256 + cg * 64)) * 1024 + s0 + p;
        float ps = 0.f;
#pragma unroll
        for (int qq = 0; qq < 4; ++qq)
#pragma unroll
            for (int ks = 0; ks < 2; ++ks) {
                float v[8];
#pragma unroll
                for (int j = 0; j < 8; ++j) {
                    v[j] = zb[(size_t)(ks * 32 + qq * 8 + j) * 1024];
                    ps = fmaf(v[j], v[j], ps);
                }
                uint2 w;
                w.x = pk4_fp8(16.f * v[0], 16.f * v[1], 16.f * v[2], 16.f * v[3]);
                w.y = pk4_fp8(16.f * v[4], 16.f * v[5], 16.f * v[6], 16.f * v[7]);
                const int pgl = cg * 4 + qq;
                const int pgs = (pgl & 8) | ((pgl & 7) ^ (p & 7));
                *(uint2*)(As + p * 256 + pgs * 16 + ks * 8) = w;
            }
        z2p[cg * 64 + p] = ps;
    }
    __syncthreads();
    if (tid < 64)
        z2[tid] = (z2p[tid] + z2p[64 + tid]) + (z2p[128 + tid] + z2p[192 + tid]);

    // ---- hoist A fragments: depend only on (kt, mt) -> 16 ds_read_b128, once ----
    longx2 faA[4][4];
#pragma unroll
    for (int kt = 0; kt < 4; ++kt)
#pragma unroll
        for (int mt = 0; mt < 4; ++mt) {
            const int p = mt * 16 + r;
            const int pgl = kt * 4 + q;
            const int pgs = (pgl & 8) | ((pgl & 7) ^ (r & 7));
            faA[kt][mt] = *(const longx2*)(As + p * 256 + pgs * 16);
        }
    __syncthreads();            // As region free -> becomes Bs buf0

    // ---- K-loop: 16 chunks of 64 codes, Bs double-buffered, prefetch depth 1 ----
    floatx4 acc[4] = {};
    unsigned run[16];
#pragma unroll
    for (int j = 0; j < 16; ++j) run[j] = 0xFFFFFFFFu;

    // prologue: stage chunk 0 into buf0 (16KB = 4 x gload16/thread, linear dest)
#pragma unroll
    for (int j = 0; j < 4; ++j)
        gload16(emb8 + (size_t)j * 65536 + tid * 16,
                (char*)smem + j * 4096 + tid * 16);

#pragma unroll 1
    for (int t = 0; t < 16; ++t) {
        __syncthreads();        // drains stage(t)'s loads; all waves past compute(t-1)
        if (t < 15) {           // issue stage(t+1) -> lands under compute(t)
            char* db = (char*)smem + (((t + 1) & 1) << 14);
            const size_t gs = (size_t)(t + 1) * 4096;
#pragma unroll
            for (int j = 0; j < 4; ++j)
                gload16(emb8 + (size_t)j * 65536 + gs + tid * 16,
                        db + j * 4096 + tid * 16);
        }
        const unsigned char* bb = (const unsigned char*)smem + ((t & 1) << 14);
        const float ev = e_sqs[t * 64 + wave * 16 + r];
#pragma unroll
        for (int kt = 0; kt < 4; ++kt) {
            const longx2 fb = *(const longx2*)(bb + kt * 4096 + (wave * 16 + r) * 64 + q * 16);
#pragma unroll
            for (int mt = 0; mt < 4; ++mt) {
                acc[mt] = __builtin_amdgcn_mfma_f32_16x16x32_fp8_fp8(
                    faA[kt][mt][0], fb[0], acc[mt], 0, 0, 0);
                acc[mt] = __builtin_amdgcn_mfma_f32_16x16x32_fp8_fp8(
                    faA[kt][mt][1], fb[1], acc[mt], 0, 0, 0);
            }
        }
        // fold: val = 16384 + 4096*e_sq - 2*dot~ ; pack (val*32)<<10 | code
        const int code = t * 64 + wave * 16 + r;
#pragma unroll
        for (int mt = 0; mt < 4; ++mt) {
#pragma unroll
            for (int reg = 0; reg < 4; ++reg) {
                float v = 16384.f + ev - 2.f * acc[mt][reg];
                unsigned pk = ((unsigned)(v * 32.f) << 10) | (unsigned)code;
                run[(mt << 2) + reg] = min(run[(mt << 2) + reg], pk);
            }
            acc[mt] = (floatx4){0.f, 0.f, 0.f, 0.f};
        }
    }

    // ---- argmin merge across lanes/waves ----
#pragma unroll
    for (int j = 0; j < 16; ++j) {
        unsigned pk = run[j];
#pragma unroll
        for (int off = 1; off < 16; off <<= 1)
            pk = min(pk, (unsigned)__shfl_xor((int)pk, off, 64));
        if (r == 0)
            red[(((j >> 2) << 4) + (q << 2) + (j & 3)) * 4 + wave] = pk;
    }
    __syncthreads();
    if (tid < 64) {
        unsigned m = min(min(red[tid * 4 + 0], red[tid * 4 + 1]),
                         min(red[tid * 4 + 2], red[tid * 4 + 3]));
        sidx[tid] = m & 1023u;
        float val = (float)(m >> 10) * (1.f / 32.f);
        float d = z2[tid] + (val - 16384.f) * (1.f / 4096.f);
#pragma unroll
        for (int off = 32; off >= 1; off >>= 1) d += __shfl_down(d, off, 64);
        if (tid == 0) atomicAdd(loss, d * (1.25f / 16777216.f));
    }
    __syncthreads();

    // ---- gather + write z_q: 2 passes of 32 rows through smG (full 128B lines) ----
#pragma unroll 1
    for (int pass = 0; pass < 2; ++pass) {
        const int rbase = pass << 5;
#pragma unroll
        for (int i = 0; i < 8; ++i) {
            const int row = wave * 8 + i;                             // 0..31
            const unsigned code = sidx[rbase + row];
            const int src_chunk = (lane & 56) | ((lane & 7) ^ (row & 7));
            gload16(emb + (size_t)code * CDIM + src_chunk * 4,
                    (char*)smem + row * 1024 + lane * 16);
        }
        __syncthreads();
        {
            const int s = tid & 31, cg = tid >> 5;                    // 32 pos x 8 ch-groups
            float* ob = out + ((size_t)(b * 256 + cg * 32)) * 1024 + s0 + rbase + s;
#pragma unroll
            for (int c4 = 0; c4 < 8; ++c4) {
                const int lc4 = cg * 8 + c4;                          // logical 16B chunk
                const int p16 = (lc4 & 56) | ((lc4 & 7) ^ (s & 7));   // swizzled position
                float4 v = *(const float4*)((const char*)smem + s * 1024 + p16 * 16);
                ob[(size_t)(c4 * 4 + 0) * 1024] = v.x;
                ob[(size_t)(c4 * 4 + 1) * 1024] = v.y;
                ob[(size_t)(c4 * 4 + 2) * 1024] = v.z;
                ob[(size_t)(c4 * 4 + 3) * 1024] = v.w;
            }
        }
        __syncthreads();
    }
}

extern "C" void kernel_launch(void* const* d_in, const int* in_sizes, int n_in,
                              void* d_out, int out_size, void* d_ws, size_t ws_size,
                              hipStream_t stream)
{
    const float* z   = (const float*)d_in[0];
    const float* emb = (const float*)d_in[1];
    float* out = (float*)d_out;

    unsigned char* emb8 = (unsigned char*)d_ws;           // 256 KB
    float* e_sqs = (float*)((char*)d_ws + 262144);        // 4 KB
    float* loss  = out + 16777216;

    hipMemsetAsync(loss, 0, sizeof(float), stream);
    emb_prep<<<KCODES, 64, 0, stream>>>(emb, emb8, e_sqs);
    vq_fused<<<1024, 256, 0, stream>>>(z, emb, emb8, e_sqs, out, loss);
}